// Round 5
// baseline (174.277 us; speedup 1.0000x reference)
//
#include <hip/hip_runtime.h>
#include <hip/hip_bf16.h>

// Problem constants (QuadraticAttention): B=2, T=2048, D_MODEL=1024, H=16, d=64
#define TSEQ   2048
#define DM     1024
#define NHEAD  16
#define DH     64
#define BATCH  2
#define MR     (BATCH * TSEQ)   // 4096 rows
#define CH     64               // attention chunk length
#define NC     (TSEQ / CH)      // 32 chunks per sequence
#define QKVLD  (3 * DM)         // 3072 fused N
#define LP     72               // padded LDS row stride (bf16)

typedef __attribute__((ext_vector_type(8))) short bf16x8;
typedef __attribute__((ext_vector_type(4))) float f32x4;

__device__ __forceinline__ short f2bf(float x) {
  __hip_bfloat16 h = __float2bfloat16(x);
  return *reinterpret_cast<short*>(&h);
}

__device__ __forceinline__ void stage16(const void* g, void* l) {
  __builtin_amdgcn_global_load_lds(
      (const __attribute__((address_space(1))) void*)g,
      (__attribute__((address_space(3))) void*)l, 16, 0, 0);
}

// ---------------------------------------------------------------------------
// Fused QKV GEMM: [4096,1024] @ [1024,3072]. 128x128 tile, BK=64 as TWO
// BK=32 panels (As[2][128][32]) -> same LDS/bank pattern as m97, half the
// barriers (16 K-iterations instead of 32).
// Epilogue by N-region: Q->qb natural; K->kb natural + kT tiles; V->vT tiles.
// ---------------------------------------------------------------------------
__global__ __launch_bounds__(256) void gemm_qkv(const short* __restrict__ A,
                                                const short* __restrict__ Bt,
                                                short* __restrict__ qb,
                                                short* __restrict__ kb,
                                                short* __restrict__ kT,
                                                short* __restrict__ vT) {
  const int K = DM;
  __shared__ short As[2][128][32];   // 16 KB
  __shared__ short Bs[2][128][32];   // 16 KB
  const int tid = threadIdx.x;
  const int lane = tid & 63, wid = tid >> 6;
  const int wave_m = wid >> 1, wave_n = wid & 1;
  const int row0 = blockIdx.y * 128, col0 = blockIdx.x * 128;

  const int sr = tid >> 2, sk = (tid & 3) * 8;   // panel slot map (64B rows)
  const short* Ag0 = A + (size_t)(row0 + sr) * K + sk;
  const short* Bg0 = Bt + (size_t)(col0 + sr) * K + sk;
  short* AsL = &As[0][0][0] + tid * 8;
  short* BsL = &Bs[0][0][0] + tid * 8;

  f32x4 acc[4][4];
#pragma unroll
  for (int i = 0; i < 4; ++i)
#pragma unroll
    for (int j = 0; j < 4; ++j) acc[i][j] = (f32x4){0.f, 0.f, 0.f, 0.f};

  const int fm = wave_m * 64 + (lane & 15);
  const int fn = wave_n * 64 + (lane & 15);
  const int fk = (lane >> 4) * 8;

  for (int k0 = 0; k0 < K; k0 += 64) {
    // panel 0: k in [k0, k0+32), panel 1: k in [k0+32, k0+64)
    stage16(Ag0 + k0, AsL);
    stage16(Ag0 + (size_t)64 * K + k0, AsL + 2048);
    stage16(Ag0 + k0 + 32, AsL + 4096);
    stage16(Ag0 + (size_t)64 * K + k0 + 32, AsL + 6144);
    stage16(Bg0 + k0, BsL);
    stage16(Bg0 + (size_t)64 * K + k0, BsL + 2048);
    stage16(Bg0 + k0 + 32, BsL + 4096);
    stage16(Bg0 + (size_t)64 * K + k0 + 32, BsL + 6144);
    __syncthreads();
#pragma unroll
    for (int p = 0; p < 2; ++p) {
      bf16x8 af[4], bf[4];
#pragma unroll
      for (int t = 0; t < 4; ++t) {
        af[t] = *(const bf16x8*)&As[p][fm + t * 16][fk];
        bf[t] = *(const bf16x8*)&Bs[p][fn + t * 16][fk];
      }
#pragma unroll
      for (int im = 0; im < 4; ++im)
#pragma unroll
        for (int jn = 0; jn < 4; ++jn)
          acc[im][jn] = __builtin_amdgcn_mfma_f32_16x16x32_bf16(af[im], bf[jn], acc[im][jn], 0, 0, 0);
    }
    __syncthreads();
  }

  const int crow = (lane >> 4) * 4, ccol = lane & 15;
  const int region = col0 >> 10;   // 0=Q, 1=K, 2=V (block-uniform)

  if (region <= 1) {
    short* Cb = (region == 0) ? qb : kb;
#pragma unroll
    for (int im = 0; im < 4; ++im)
#pragma unroll
      for (int jn = 0; jn < 4; ++jn) {
        const int gr = row0 + wave_m * 64 + im * 16 + crow;
        const int gc = (col0 & 1023) + wave_n * 64 + jn * 16 + ccol;
        short* Cp = Cb + (size_t)gr * DM + gc;
#pragma unroll
        for (int r = 0; r < 4; ++r) Cp[(size_t)r * DM] = f2bf(acc[im][jn][r]);
      }
  }
  if (region >= 1) {
    short* Tt = (region == 1) ? kT : vT;
    const int gr0 = row0 + wave_m * 64;         // chunk-aligned (64 rows)
    const int b = gr0 >> 11;
    const int c = (gr0 & 2047) >> 6;
#pragma unroll
    for (int im = 0; im < 4; ++im)
#pragma unroll
      for (int jn = 0; jn < 4; ++jn) {
        const int gcol = (col0 & 1023) + wave_n * 64 + jn * 16 + ccol;
        const int h = gcol >> 6, i = gcol & 63;
        const int s0 = im * 16 + crow;          // 4 consecutive s per lane
        size_t idx = ((((size_t)(b * NHEAD + h) * NC + c) * DH + i) * DH + s0);
        union { short h4[4]; uint2 u; } pk;
#pragma unroll
        for (int r = 0; r < 4; ++r) pk.h4[r] = f2bf(acc[im][jn][r]);
        *(uint2*)(Tt + idx) = pk.u;
      }
  }
}

// ---------------------------------------------------------------------------
// Output projection GEMM: [4096,1024] @ [1024,1024] -> fp32.
// 128Mx64N tile, BK=32, 512 blocks (2 blocks/CU vs 1 for 128x128).
// Wave w owns rows [32w, 32w+32); acc 2x4 tiles.
// ---------------------------------------------------------------------------
__global__ __launch_bounds__(256) void gemm_out(const short* __restrict__ A,
                                                const short* __restrict__ Bt,
                                                float* __restrict__ C) {
  const int K = DM, N = DM;
  __shared__ short As[128][32];  // 8 KB
  __shared__ short Bs[64][32];   // 4 KB
  const int tid = threadIdx.x, lane = tid & 63, wid = tid >> 6;
  const int row0 = blockIdx.y * 128, col0 = blockIdx.x * 64;

  const int sr = tid >> 2, sk = (tid & 3) * 8;
  const short* Ag0 = A + (size_t)(row0 + sr) * K + sk;
  const short* Bg0 = Bt + (size_t)(col0 + sr) * K + sk;   // rows 0..63
  short* AsL = &As[0][0] + tid * 8;
  short* BsL = &Bs[0][0] + tid * 8;   // 256 slots = full 64x32 panel

  f32x4 acc[2][4];
#pragma unroll
  for (int i = 0; i < 2; ++i)
#pragma unroll
    for (int j = 0; j < 4; ++j) acc[i][j] = (f32x4){0.f, 0.f, 0.f, 0.f};

  const int fm = wid * 32 + (lane & 15);
  const int fn = lane & 15;
  const int fk = (lane >> 4) * 8;

  for (int k0 = 0; k0 < K; k0 += 32) {
    stage16(Ag0 + k0, AsL);
    stage16(Ag0 + (size_t)64 * K + k0, AsL + 2048);
    stage16(Bg0 + k0, BsL);
    __syncthreads();
    bf16x8 af[2], bf[4];
#pragma unroll
    for (int t = 0; t < 2; ++t) af[t] = *(const bf16x8*)&As[fm + t * 16][fk];
#pragma unroll
    for (int t = 0; t < 4; ++t) bf[t] = *(const bf16x8*)&Bs[t * 16 + fn][fk];
#pragma unroll
    for (int im = 0; im < 2; ++im)
#pragma unroll
      for (int jn = 0; jn < 4; ++jn)
        acc[im][jn] = __builtin_amdgcn_mfma_f32_16x16x32_bf16(af[im], bf[jn], acc[im][jn], 0, 0, 0);
    __syncthreads();
  }

  const int crow = (lane >> 4) * 4, ccol = lane & 15;
#pragma unroll
  for (int im = 0; im < 2; ++im)
#pragma unroll
    for (int jn = 0; jn < 4; ++jn) {
      float* Cp = C + (size_t)(row0 + wid * 32 + im * 16 + crow) * N
                    + col0 + jn * 16 + ccol;
#pragma unroll
      for (int r = 0; r < 4; ++r) Cp[(size_t)r * N] = acc[im][jn][r];
    }
}

// ---------------------------------------------------------------------------
// prep: z<4 -> transpose W_z (fp32 [K][N] -> bf16 [N][K]); z==4 -> x fp32->bf16.
// ---------------------------------------------------------------------------
__global__ __launch_bounds__(256) void prep(const float* __restrict__ x,
                                            const float* __restrict__ W0,
                                            const float* __restrict__ W1,
                                            const float* __restrict__ W2,
                                            const float* __restrict__ W3,
                                            __hip_bfloat16* __restrict__ xb,
                                            __hip_bfloat16* __restrict__ Wt) {
  const int tid = threadIdx.x;
  if (blockIdx.z == 4) {
    const int bid = blockIdx.y * 16 + blockIdx.x;
    const float* src = x + (size_t)bid * 16384;
    __hip_bfloat16* dst = xb + (size_t)bid * 16384;
#pragma unroll
    for (int it = 0; it < 16; ++it) {
      int i = it * 1024 + tid * 4;
      float4 v = *(const float4*)(src + i);
      union { __hip_bfloat16 h[4]; uint2 u; } pk;
      pk.h[0] = __float2bfloat16(v.x); pk.h[1] = __float2bfloat16(v.y);
      pk.h[2] = __float2bfloat16(v.z); pk.h[3] = __float2bfloat16(v.w);
      *(uint2*)(dst + i) = pk.u;
    }
    return;
  }
  const float* W = blockIdx.z == 0 ? W0 : blockIdx.z == 1 ? W1 : blockIdx.z == 2 ? W2 : W3;
  __hip_bfloat16* out = Wt + (size_t)blockIdx.z * DM * DM;
  __shared__ float tile[64][65];
  const int kt = blockIdx.y * 64, nt = blockIdx.x * 64;
  const int lr = tid >> 6, lc = tid & 63;
#pragma unroll
  for (int i = 0; i < 16; ++i) {
    int k = i * 4 + lr;
    tile[k][lc] = W[(size_t)(kt + k) * DM + nt + lc];
  }
  __syncthreads();
  const int nl = tid >> 4, k4 = (tid & 15) * 4;
#pragma unroll
  for (int i = 0; i < 4; ++i) {
    int n = i * 16 + nl;
    union { __hip_bfloat16 h[4]; uint2 u; } pk;
#pragma unroll
    for (int xx = 0; xx < 4; ++xx) pk.h[xx] = __float2bfloat16(tile[k4 + xx][n]);
    *(uint2*)(out + (size_t)(nt + n) * DM + kt + k4) = pk.u;
  }
}

// ---------------------------------------------------------------------------
// Fused Phase A+B: exclusive prefix-scanned chunk states, state in registers.
// Grid (4, NHEAD, BATCH); block js owns j-rows [16js,16js+16); wave w owns
// i-cols [16w,16w+16). Per chunk: write exclusive state (bf16), then
// run += V^T[j][s] * K^T[i][s] via 2 MFMAs. No Mc round-trip.
// ---------------------------------------------------------------------------
__global__ __launch_bounds__(256) void state_scan(const short* __restrict__ kT,
                                                  const short* __restrict__ vT,
                                                  short* __restrict__ Spre) {
  const int js = blockIdx.x, h = blockIdx.y, b = blockIdx.z;
  const int tid = threadIdx.x, lane = tid & 63, w = tid >> 6;
  const int m = lane & 15, q = lane >> 4;
  const size_t hbase = ((size_t)(b * NHEAD + h) * NC) * (DH * DH);
  const int jrow = 16 * js + m;   // A-frag row (j)
  const int irow = 16 * w + m;    // B-frag row (i)
  f32x4 run = (f32x4){0.f, 0.f, 0.f, 0.f};
  for (int c = 0; c < NC; ++c) {
    const size_t tile = hbase + (size_t)c * (DH * DH);
    // exclusive: state BEFORE chunk c. D elems: j = 16js+q*4+rr, i = 16w+m.
#pragma unroll
    for (int rr = 0; rr < 4; ++rr)
      Spre[tile + (size_t)(16 * js + q * 4 + rr) * DH + 16 * w + m] = f2bf(run[rr]);
    bf16x8 a0 = *(const bf16x8*)(vT + tile + (size_t)jrow * DH + q * 8);
    bf16x8 a1 = *(const bf16x8*)(vT + tile + (size_t)jrow * DH + q * 8 + 32);
    bf16x8 b0 = *(const bf16x8*)(kT + tile + (size_t)irow * DH + q * 8);
    bf16x8 b1 = *(const bf16x8*)(kT + tile + (size_t)irow * DH + q * 8 + 32);
    f32x4 t = (f32x4){0.f, 0.f, 0.f, 0.f};
    t = __builtin_amdgcn_mfma_f32_16x16x32_bf16(a0, b0, t, 0, 0, 0);
    t = __builtin_amdgcn_mfma_f32_16x16x32_bf16(a1, b1, t, 0, 0, 0);
    run += t;
  }
}

// ---------------------------------------------------------------------------
// Phase C (MFMA, transposed orientation): per (b,h,chunk),
//   O^T[j][t] = sum_i St[j][i] Q[t][i] + sum_s V^T[j][s] P[t][s]
// ---------------------------------------------------------------------------
__global__ __launch_bounds__(256) void intra_attn(const short* __restrict__ qb,
                                                  const short* __restrict__ kb,
                                                  const short* __restrict__ vT,
                                                  const short* __restrict__ Spre,
                                                  short* __restrict__ O_) {
  const int c = blockIdx.x, h = blockIdx.y, b = blockIdx.z;
  __shared__ short Qs[CH][LP];
  __shared__ short Ks[CH][LP];   // K -> then P
  const int tid = threadIdx.x, lane = tid & 63, w = tid >> 6;
  const int m = lane & 15, q = lane >> 4;
  const int r = tid >> 2, q16 = (tid & 3) * 16;
  const size_t tile = ((size_t)(b * NHEAD + h) * NC + c) * (DH * DH);
  const size_t grow = ((size_t)(b * TSEQ + c * CH + r)) * DM + h * DH;
  *(bf16x8*)&Qs[r][q16]     = *(const bf16x8*)(qb + grow + q16);
  *(bf16x8*)&Qs[r][q16 + 8] = *(const bf16x8*)(qb + grow + q16 + 8);
  *(bf16x8*)&Ks[r][q16]     = *(const bf16x8*)(kb + grow + q16);
  *(bf16x8*)&Ks[r][q16 + 8] = *(const bf16x8*)(kb + grow + q16 + 8);
  const short* vt = vT + tile;
  const short* st = Spre + tile;
  bf16x8 av0 = *(const bf16x8*)(vt + (16 * w + m) * DH + q * 8);
  bf16x8 av1 = *(const bf16x8*)(vt + (16 * w + m) * DH + q * 8 + 32);
  bf16x8 as0 = *(const bf16x8*)(st + (16 * w + m) * DH + q * 8);
  bf16x8 as1 = *(const bf16x8*)(st + (16 * w + m) * DH + q * 8 + 32);
  __syncthreads();

  bf16x8 aq0 = *(const bf16x8*)&Qs[16 * w + m][q * 8];
  bf16x8 aq1 = *(const bf16x8*)&Qs[16 * w + m][q * 8 + 32];

  f32x4 acc[4], pacc[4];
#pragma unroll
  for (int ct = 0; ct < 4; ++ct) {
    acc[ct] = (f32x4){0.f, 0.f, 0.f, 0.f};
    pacc[ct] = (f32x4){0.f, 0.f, 0.f, 0.f};
  }
#pragma unroll
  for (int ct = 0; ct < 4; ++ct) {
    bf16x8 bq0 = *(const bf16x8*)&Qs[ct * 16 + m][q * 8];
    bf16x8 bq1 = *(const bf16x8*)&Qs[ct * 16 + m][q * 8 + 32];
    acc[ct] = __builtin_amdgcn_mfma_f32_16x16x32_bf16(as0, bq0, acc[ct], 0, 0, 0);
    acc[ct] = __builtin_amdgcn_mfma_f32_16x16x32_bf16(as1, bq1, acc[ct], 0, 0, 0);
    bf16x8 bk0 = *(const bf16x8*)&Ks[ct * 16 + m][q * 8];
    bf16x8 bk1 = *(const bf16x8*)&Ks[ct * 16 + m][q * 8 + 32];
    pacc[ct] = __builtin_amdgcn_mfma_f32_16x16x32_bf16(aq0, bk0, pacc[ct], 0, 0, 0);
    pacc[ct] = __builtin_amdgcn_mfma_f32_16x16x32_bf16(aq1, bk1, pacc[ct], 0, 0, 0);
  }
  __syncthreads();
#pragma unroll
  for (int ct = 0; ct < 4; ++ct) {
    const int s = ct * 16 + m;
#pragma unroll
    for (int rr = 0; rr < 4; ++rr) {
      const int t = 16 * w + q * 4 + rr;
      Ks[t][s] = f2bf((s < t) ? pacc[ct][rr] : 0.f);
    }
  }
  __syncthreads();
#pragma unroll
  for (int ct = 0; ct < 4; ++ct) {
    bf16x8 bp0 = *(const bf16x8*)&Ks[ct * 16 + m][q * 8];
    bf16x8 bp1 = *(const bf16x8*)&Ks[ct * 16 + m][q * 8 + 32];
    acc[ct] = __builtin_amdgcn_mfma_f32_16x16x32_bf16(av0, bp0, acc[ct], 0, 0, 0);
    acc[ct] = __builtin_amdgcn_mfma_f32_16x16x32_bf16(av1, bp1, acc[ct], 0, 0, 0);
  }
#pragma unroll
  for (int ct = 0; ct < 4; ++ct) {
    const int t = ct * 16 + m, j0 = 16 * w + q * 4;
    union { short h4[4]; uint2 u; } pk;
#pragma unroll
    for (int rr = 0; rr < 4; ++rr) pk.h4[rr] = f2bf(acc[ct][rr]);
    *(uint2*)(O_ + ((size_t)(b * TSEQ + c * CH + t)) * DM + h * DH + j0) = pk.u;
  }
}

// ---------------------------------------------------------------------------
extern "C" void kernel_launch(void* const* d_in, const int* in_sizes, int n_in,
                              void* d_out, int out_size, void* d_ws, size_t ws_size,
                              hipStream_t stream) {
  const float* x  = (const float*)d_in[0];
  const float* Wq = (const float*)d_in[1];
  const float* Wk = (const float*)d_in[2];
  const float* Wv = (const float*)d_in[3];
  const float* Wo = (const float*)d_in[4];
  float* out = (float*)d_out;

  char* ws = (char*)d_ws;
  short* xb    = (short*)ws;  ws += (size_t)MR * DM * 2;     // 8 MB
  short* WtAll = (short*)ws;  ws += (size_t)4 * DM * DM * 2; // 8 MB
  short* qb    = (short*)ws;  ws += (size_t)MR * DM * 2;     // 8 MB
  short* kb    = (short*)ws;  ws += (size_t)MR * DM * 2;     // 8 MB
  short* kT    = (short*)ws;  ws += (size_t)MR * DM * 2;     // 8 MB
  short* vT    = (short*)ws;  ws += (size_t)MR * DM * 2;     // 8 MB
  short* Spre  = (short*)ws;  ws += (size_t)MR * DM * 2;     // 8 MB
  short* aob   = (short*)ws;  ws += (size_t)MR * DM * 2;     // 8 MB

  prep<<<dim3(16, 16, 5), 256, 0, stream>>>(x, Wq, Wk, Wv, Wo,
                                            (__hip_bfloat16*)xb, (__hip_bfloat16*)WtAll);

  gemm_qkv<<<dim3(QKVLD / 128, MR / 128), 256, 0, stream>>>(xb, WtAll, qb, kb, kT, vT);

  state_scan<<<dim3(4, NHEAD, BATCH), 256, 0, stream>>>(kT, vT, Spre);

  intra_attn<<<dim3(NC, NHEAD, BATCH), 256, 0, stream>>>(qb, kb, vT, Spre, aob);

  gemm_out<<<dim3(DM / 64, MR / 128), 256, 0, stream>>>(
      aob, WtAll + (size_t)3 * DM * DM, out);
}

// Round 6
// 172.901 us; speedup vs baseline: 1.0080x; 1.0080x over previous
//
#include <hip/hip_runtime.h>
#include <hip/hip_bf16.h>

// Problem constants (QuadraticAttention): B=2, T=2048, D_MODEL=1024, H=16, d=64
#define TSEQ   2048
#define DM     1024
#define NHEAD  16
#define DH     64
#define BATCH  2
#define MR     (BATCH * TSEQ)   // 4096 rows
#define CH     64               // attention chunk length
#define NC     (TSEQ / CH)      // 32 chunks per sequence
#define QKVLD  (3 * DM)         // 3072 fused N
#define LP     72               // padded LDS row stride (bf16)

typedef __attribute__((ext_vector_type(8))) short bf16x8;
typedef __attribute__((ext_vector_type(4))) float f32x4;
typedef __attribute__((ext_vector_type(16))) float f32x16;

__device__ __forceinline__ short f2bf(float x) {
  __hip_bfloat16 h = __float2bfloat16(x);
  return *reinterpret_cast<short*>(&h);
}

__device__ __forceinline__ void stage16(const void* g, void* l) {
  __builtin_amdgcn_global_load_lds(
      (const __attribute__((address_space(1))) void*)g,
      (__attribute__((address_space(3))) void*)l, 16, 0, 0);
}

// ---------------------------------------------------------------------------
// Fused QKV GEMM: [4096,1024] @ [1024,3072]. 128x128 tile, BK=32 (16 KB LDS,
// the R4 occupancy sweet spot), K-loop on v_mfma_f32_32x32x16_bf16:
// per wave 2x2 tiles of 32x32, 8 MFMA + 8 ds_read_b128 per panel.
// C/D layout: col=lane&31, row=(reg&3)+8*(reg>>2)+4*(lane>>5)  [m74/m101].
// Epilogue by N-region: Q->qb natural; K->kb natural + kT tiles; V->vT tiles.
// ---------------------------------------------------------------------------
__global__ __launch_bounds__(256) void gemm_qkv(const short* __restrict__ A,
                                                const short* __restrict__ Bt,
                                                short* __restrict__ qb,
                                                short* __restrict__ kb,
                                                short* __restrict__ kT,
                                                short* __restrict__ vT) {
  const int K = DM;
  __shared__ short As[128][32];   // 8 KB
  __shared__ short Bs[128][32];   // 8 KB
  const int tid = threadIdx.x;
  const int lane = tid & 63, wid = tid >> 6;
  const int wave_m = wid >> 1, wave_n = wid & 1;
  const int row0 = blockIdx.y * 128, col0 = blockIdx.x * 128;

  const int sr = tid >> 2, sk = (tid & 3) * 8;
  const short* Ag0 = A + (size_t)(row0 + sr) * K + sk;
  const short* Bg0 = Bt + (size_t)(col0 + sr) * K + sk;
  short* AsL = &As[0][0] + tid * 8;
  short* BsL = &Bs[0][0] + tid * 8;

  f32x16 acc[2][2];
#pragma unroll
  for (int i = 0; i < 2; ++i)
#pragma unroll
    for (int j = 0; j < 2; ++j)
#pragma unroll
      for (int e = 0; e < 16; ++e) acc[i][j][e] = 0.f;

  const int l31 = lane & 31, l5 = lane >> 5;
  const int fm = wave_m * 64 + l31;   // + tm*32
  const int fn = wave_n * 64 + l31;   // + tn*32
  const int fk = l5 * 8;              // + kk*16

  for (int k0 = 0; k0 < K; k0 += 32) {
    stage16(Ag0 + k0, AsL);
    stage16(Ag0 + (size_t)64 * K + k0, AsL + 2048);
    stage16(Bg0 + k0, BsL);
    stage16(Bg0 + (size_t)64 * K + k0, BsL + 2048);
    __syncthreads();
    bf16x8 af[2][2], bf[2][2];   // [tile][kk]
#pragma unroll
    for (int t = 0; t < 2; ++t)
#pragma unroll
      for (int kk = 0; kk < 2; ++kk) {
        af[t][kk] = *(const bf16x8*)&As[fm + t * 32][fk + kk * 16];
        bf[t][kk] = *(const bf16x8*)&Bs[fn + t * 32][fk + kk * 16];
      }
#pragma unroll
    for (int tm = 0; tm < 2; ++tm)
#pragma unroll
      for (int tn = 0; tn < 2; ++tn)
#pragma unroll
        for (int kk = 0; kk < 2; ++kk)
          acc[tm][tn] = __builtin_amdgcn_mfma_f32_32x32x16_bf16(
              af[tm][kk], bf[tn][kk], acc[tm][tn], 0, 0, 0);
    __syncthreads();
  }

  const int region = col0 >> 10;   // 0=Q, 1=K, 2=V (block-uniform)

  if (region <= 1) {
    short* Cb = (region == 0) ? qb : kb;
#pragma unroll
    for (int tm = 0; tm < 2; ++tm)
#pragma unroll
      for (int tn = 0; tn < 2; ++tn) {
        const int gc = (col0 & 1023) + wave_n * 64 + tn * 32 + l31;
        const int gr_base = row0 + wave_m * 64 + tm * 32 + 4 * l5;
#pragma unroll
        for (int g = 0; g < 4; ++g)
#pragma unroll
          for (int rr = 0; rr < 4; ++rr) {
            const int gr = gr_base + g * 8 + rr;
            Cb[(size_t)gr * DM + gc] = f2bf(acc[tm][tn][g * 4 + rr]);
          }
      }
  }
  if (region >= 1) {
    short* Tt = (region == 1) ? kT : vT;
    const int gr0 = row0 + wave_m * 64;   // chunk-aligned only if tm handled below
    const int b = (row0) >> 11;
    // rows of this wave: row0 + wave_m*64 + tm*32 + ... all within one 64-chunk
    const int c = ((row0 + wave_m * 64) & 2047) >> 6;
#pragma unroll
    for (int tm = 0; tm < 2; ++tm)
#pragma unroll
      for (int tn = 0; tn < 2; ++tn) {
        const int gcol = (col0 & 1023) + wave_n * 64 + tn * 32 + l31;
        const int h = gcol >> 6, i = gcol & 63;
        const int s_base = (wave_m & 1) * 0 + tm * 32 + 4 * l5;   // s within chunk: local 64 rows
#pragma unroll
        for (int g = 0; g < 4; ++g) {
          const int s0 = tm * 32 + g * 8 + 4 * l5;   // 4 consecutive s from reg quad
          union { short h4[4]; uint2 u; } pk;
#pragma unroll
          for (int rr = 0; rr < 4; ++rr) pk.h4[rr] = f2bf(acc[tm][tn][g * 4 + rr]);
          size_t idx = ((((size_t)(b * NHEAD + h) * NC + c) * DH + i) * DH + s0);
          *(uint2*)(Tt + idx) = pk.u;
        }
      }
  }
}

// ---------------------------------------------------------------------------
// Output projection GEMM: [4096,1024] @ [1024,1024] -> fp32.
// 128Mx64N tile, BK=32, 512 blocks (2 blocks/CU).
// ---------------------------------------------------------------------------
__global__ __launch_bounds__(256) void gemm_out(const short* __restrict__ A,
                                                const short* __restrict__ Bt,
                                                float* __restrict__ C) {
  const int K = DM, N = DM;
  __shared__ short As[128][32];  // 8 KB
  __shared__ short Bs[64][32];   // 4 KB
  const int tid = threadIdx.x, lane = tid & 63, wid = tid >> 6;
  const int row0 = blockIdx.y * 128, col0 = blockIdx.x * 64;

  const int sr = tid >> 2, sk = (tid & 3) * 8;
  const short* Ag0 = A + (size_t)(row0 + sr) * K + sk;
  const short* Bg0 = Bt + (size_t)(col0 + sr) * K + sk;
  short* AsL = &As[0][0] + tid * 8;
  short* BsL = &Bs[0][0] + tid * 8;

  f32x4 acc[2][4];
#pragma unroll
  for (int i = 0; i < 2; ++i)
#pragma unroll
    for (int j = 0; j < 4; ++j) acc[i][j] = (f32x4){0.f, 0.f, 0.f, 0.f};

  const int fm = wid * 32 + (lane & 15);
  const int fn = lane & 15;
  const int fk = (lane >> 4) * 8;

  for (int k0 = 0; k0 < K; k0 += 32) {
    stage16(Ag0 + k0, AsL);
    stage16(Ag0 + (size_t)64 * K + k0, AsL + 2048);
    stage16(Bg0 + k0, BsL);
    __syncthreads();
    bf16x8 af[2], bf[4];
#pragma unroll
    for (int t = 0; t < 2; ++t) af[t] = *(const bf16x8*)&As[fm + t * 16][fk];
#pragma unroll
    for (int t = 0; t < 4; ++t) bf[t] = *(const bf16x8*)&Bs[t * 16 + fn][fk];
#pragma unroll
    for (int im = 0; im < 2; ++im)
#pragma unroll
      for (int jn = 0; jn < 4; ++jn)
        acc[im][jn] = __builtin_amdgcn_mfma_f32_16x16x32_bf16(af[im], bf[jn], acc[im][jn], 0, 0, 0);
    __syncthreads();
  }

  const int crow = (lane >> 4) * 4, ccol = lane & 15;
#pragma unroll
  for (int im = 0; im < 2; ++im)
#pragma unroll
    for (int jn = 0; jn < 4; ++jn) {
      float* Cp = C + (size_t)(row0 + wid * 32 + im * 16 + crow) * N
                    + col0 + jn * 16 + ccol;
#pragma unroll
      for (int r = 0; r < 4; ++r) Cp[(size_t)r * N] = acc[im][jn][r];
    }
}

// ---------------------------------------------------------------------------
// prep: z<4 -> transpose W_z (fp32 [K][N] -> bf16 [N][K]); z==4 -> x fp32->bf16.
// ---------------------------------------------------------------------------
__global__ __launch_bounds__(256) void prep(const float* __restrict__ x,
                                            const float* __restrict__ W0,
                                            const float* __restrict__ W1,
                                            const float* __restrict__ W2,
                                            const float* __restrict__ W3,
                                            __hip_bfloat16* __restrict__ xb,
                                            __hip_bfloat16* __restrict__ Wt) {
  const int tid = threadIdx.x;
  if (blockIdx.z == 4) {
    const int bid = blockIdx.y * 16 + blockIdx.x;
    const float* src = x + (size_t)bid * 16384;
    __hip_bfloat16* dst = xb + (size_t)bid * 16384;
#pragma unroll
    for (int it = 0; it < 16; ++it) {
      int i = it * 1024 + tid * 4;
      float4 v = *(const float4*)(src + i);
      union { __hip_bfloat16 h[4]; uint2 u; } pk;
      pk.h[0] = __float2bfloat16(v.x); pk.h[1] = __float2bfloat16(v.y);
      pk.h[2] = __float2bfloat16(v.z); pk.h[3] = __float2bfloat16(v.w);
      *(uint2*)(dst + i) = pk.u;
    }
    return;
  }
  const float* W = blockIdx.z == 0 ? W0 : blockIdx.z == 1 ? W1 : blockIdx.z == 2 ? W2 : W3;
  __hip_bfloat16* out = Wt + (size_t)blockIdx.z * DM * DM;
  __shared__ float tile[64][65];
  const int kt = blockIdx.y * 64, nt = blockIdx.x * 64;
  const int lr = tid >> 6, lc = tid & 63;
#pragma unroll
  for (int i = 0; i < 16; ++i) {
    int k = i * 4 + lr;
    tile[k][lc] = W[(size_t)(kt + k) * DM + nt + lc];
  }
  __syncthreads();
  const int nl = tid >> 4, k4 = (tid & 15) * 4;
#pragma unroll
  for (int i = 0; i < 4; ++i) {
    int n = i * 16 + nl;
    union { __hip_bfloat16 h[4]; uint2 u; } pk;
#pragma unroll
    for (int xx = 0; xx < 4; ++xx) pk.h[xx] = __float2bfloat16(tile[k4 + xx][n]);
    *(uint2*)(out + (size_t)(nt + n) * DM + kt + k4) = pk.u;
  }
}

// ---------------------------------------------------------------------------
// Fused Phase A+B: exclusive prefix-scanned chunk states, state in registers.
// ---------------------------------------------------------------------------
__global__ __launch_bounds__(256) void state_scan(const short* __restrict__ kT,
                                                  const short* __restrict__ vT,
                                                  short* __restrict__ Spre) {
  const int js = blockIdx.x, h = blockIdx.y, b = blockIdx.z;
  const int tid = threadIdx.x, lane = tid & 63, w = tid >> 6;
  const int m = lane & 15, q = lane >> 4;
  const size_t hbase = ((size_t)(b * NHEAD + h) * NC) * (DH * DH);
  const int jrow = 16 * js + m;
  const int irow = 16 * w + m;
  f32x4 run = (f32x4){0.f, 0.f, 0.f, 0.f};
  for (int c = 0; c < NC; ++c) {
    const size_t tile = hbase + (size_t)c * (DH * DH);
#pragma unroll
    for (int rr = 0; rr < 4; ++rr)
      Spre[tile + (size_t)(16 * js + q * 4 + rr) * DH + 16 * w + m] = f2bf(run[rr]);
    bf16x8 a0 = *(const bf16x8*)(vT + tile + (size_t)jrow * DH + q * 8);
    bf16x8 a1 = *(const bf16x8*)(vT + tile + (size_t)jrow * DH + q * 8 + 32);
    bf16x8 b0 = *(const bf16x8*)(kT + tile + (size_t)irow * DH + q * 8);
    bf16x8 b1 = *(const bf16x8*)(kT + tile + (size_t)irow * DH + q * 8 + 32);
    f32x4 t = (f32x4){0.f, 0.f, 0.f, 0.f};
    t = __builtin_amdgcn_mfma_f32_16x16x32_bf16(a0, b0, t, 0, 0, 0);
    t = __builtin_amdgcn_mfma_f32_16x16x32_bf16(a1, b1, t, 0, 0, 0);
    run += t;
  }
}

// ---------------------------------------------------------------------------
// Phase C (MFMA, transposed orientation): per (b,h,chunk),
//   O^T[j][t] = sum_i St[j][i] Q[t][i] + sum_s V^T[j][s] P[t][s]
// ---------------------------------------------------------------------------
__global__ __launch_bounds__(256) void intra_attn(const short* __restrict__ qb,
                                                  const short* __restrict__ kb,
                                                  const short* __restrict__ vT,
                                                  const short* __restrict__ Spre,
                                                  short* __restrict__ O_) {
  const int c = blockIdx.x, h = blockIdx.y, b = blockIdx.z;
  __shared__ short Qs[CH][LP];
  __shared__ short Ks[CH][LP];   // K -> then P
  const int tid = threadIdx.x, lane = tid & 63, w = tid >> 6;
  const int m = lane & 15, q = lane >> 4;
  const int r = tid >> 2, q16 = (tid & 3) * 16;
  const size_t tile = ((size_t)(b * NHEAD + h) * NC + c) * (DH * DH);
  const size_t grow = ((size_t)(b * TSEQ + c * CH + r)) * DM + h * DH;
  *(bf16x8*)&Qs[r][q16]     = *(const bf16x8*)(qb + grow + q16);
  *(bf16x8*)&Qs[r][q16 + 8] = *(const bf16x8*)(qb + grow + q16 + 8);
  *(bf16x8*)&Ks[r][q16]     = *(const bf16x8*)(kb + grow + q16);
  *(bf16x8*)&Ks[r][q16 + 8] = *(const bf16x8*)(kb + grow + q16 + 8);
  const short* vt = vT + tile;
  const short* st = Spre + tile;
  bf16x8 av0 = *(const bf16x8*)(vt + (16 * w + m) * DH + q * 8);
  bf16x8 av1 = *(const bf16x8*)(vt + (16 * w + m) * DH + q * 8 + 32);
  bf16x8 as0 = *(const bf16x8*)(st + (16 * w + m) * DH + q * 8);
  bf16x8 as1 = *(const bf16x8*)(st + (16 * w + m) * DH + q * 8 + 32);
  __syncthreads();

  bf16x8 aq0 = *(const bf16x8*)&Qs[16 * w + m][q * 8];
  bf16x8 aq1 = *(const bf16x8*)&Qs[16 * w + m][q * 8 + 32];

  f32x4 acc[4], pacc[4];
#pragma unroll
  for (int ct = 0; ct < 4; ++ct) {
    acc[ct] = (f32x4){0.f, 0.f, 0.f, 0.f};
    pacc[ct] = (f32x4){0.f, 0.f, 0.f, 0.f};
  }
#pragma unroll
  for (int ct = 0; ct < 4; ++ct) {
    bf16x8 bq0 = *(const bf16x8*)&Qs[ct * 16 + m][q * 8];
    bf16x8 bq1 = *(const bf16x8*)&Qs[ct * 16 + m][q * 8 + 32];
    acc[ct] = __builtin_amdgcn_mfma_f32_16x16x32_bf16(as0, bq0, acc[ct], 0, 0, 0);
    acc[ct] = __builtin_amdgcn_mfma_f32_16x16x32_bf16(as1, bq1, acc[ct], 0, 0, 0);
    bf16x8 bk0 = *(const bf16x8*)&Ks[ct * 16 + m][q * 8];
    bf16x8 bk1 = *(const bf16x8*)&Ks[ct * 16 + m][q * 8 + 32];
    pacc[ct] = __builtin_amdgcn_mfma_f32_16x16x32_bf16(aq0, bk0, pacc[ct], 0, 0, 0);
    pacc[ct] = __builtin_amdgcn_mfma_f32_16x16x32_bf16(aq1, bk1, pacc[ct], 0, 0, 0);
  }
  __syncthreads();
#pragma unroll
  for (int ct = 0; ct < 4; ++ct) {
    const int s = ct * 16 + m;
#pragma unroll
    for (int rr = 0; rr < 4; ++rr) {
      const int t = 16 * w + q * 4 + rr;
      Ks[t][s] = f2bf((s < t) ? pacc[ct][rr] : 0.f);
    }
  }
  __syncthreads();
#pragma unroll
  for (int ct = 0; ct < 4; ++ct) {
    bf16x8 bp0 = *(const bf16x8*)&Ks[ct * 16 + m][q * 8];
    bf16x8 bp1 = *(const bf16x8*)&Ks[ct * 16 + m][q * 8 + 32];
    acc[ct] = __builtin_amdgcn_mfma_f32_16x16x32_bf16(av0, bp0, acc[ct], 0, 0, 0);
    acc[ct] = __builtin_amdgcn_mfma_f32_16x16x32_bf16(av1, bp1, acc[ct], 0, 0, 0);
  }
#pragma unroll
  for (int ct = 0; ct < 4; ++ct) {
    const int t = ct * 16 + m, j0 = 16 * w + q * 4;
    union { short h4[4]; uint2 u; } pk;
#pragma unroll
    for (int rr = 0; rr < 4; ++rr) pk.h4[rr] = f2bf(acc[ct][rr]);
    *(uint2*)(O_ + ((size_t)(b * TSEQ + c * CH + t)) * DM + h * DH + j0) = pk.u;
  }
}

// ---------------------------------------------------------------------------
extern "C" void kernel_launch(void* const* d_in, const int* in_sizes, int n_in,
                              void* d_out, int out_size, void* d_ws, size_t ws_size,
                              hipStream_t stream) {
  const float* x  = (const float*)d_in[0];
  const float* Wq = (const float*)d_in[1];
  const float* Wk = (const float*)d_in[2];
  const float* Wv = (const float*)d_in[3];
  const float* Wo = (const float*)d_in[4];
  float* out = (float*)d_out;

  char* ws = (char*)d_ws;
  short* xb    = (short*)ws;  ws += (size_t)MR * DM * 2;     // 8 MB
  short* WtAll = (short*)ws;  ws += (size_t)4 * DM * DM * 2; // 8 MB
  short* qb    = (short*)ws;  ws += (size_t)MR * DM * 2;     // 8 MB
  short* kb    = (short*)ws;  ws += (size_t)MR * DM * 2;     // 8 MB
  short* kT    = (short*)ws;  ws += (size_t)MR * DM * 2;     // 8 MB
  short* vT    = (short*)ws;  ws += (size_t)MR * DM * 2;     // 8 MB
  short* Spre  = (short*)ws;  ws += (size_t)MR * DM * 2;     // 8 MB
  short* aob   = (short*)ws;  ws += (size_t)MR * DM * 2;     // 8 MB

  prep<<<dim3(16, 16, 5), 256, 0, stream>>>(x, Wq, Wk, Wv, Wo,
                                            (__hip_bfloat16*)xb, (__hip_bfloat16*)WtAll);

  gemm_qkv<<<dim3(QKVLD / 128, MR / 128), 256, 0, stream>>>(xb, WtAll, qb, kb, kT, vT);

  state_scan<<<dim3(4, NHEAD, BATCH), 256, 0, stream>>>(kT, vT, Spre);

  intra_attn<<<dim3(NC, NHEAD, BATCH), 256, 0, stream>>>(qb, kb, vT, Spre, aob);

  gemm_out<<<dim3(DM / 64, MR / 128), 256, 0, stream>>>(
      aob, WtAll + (size_t)3 * DM * DM, out);
}